// Round 3
// baseline (549.007 us; speedup 1.0000x reference)
//
#include <hip/hip_runtime.h>
#include <cmath>

typedef unsigned short u16;
typedef __bf16 bf16x8 __attribute__((ext_vector_type(8)));
typedef float f32x4 __attribute__((ext_vector_type(4)));

#define DEVI __device__ __forceinline__

DEVI float b2f(u16 u){ union{unsigned int i; float f;} v; v.i=(unsigned int)u<<16; return v.f; }
DEVI u16 f2b(float f){ union{unsigned int i; float f;} v; v.f=f;
    unsigned int r=(v.i+0x7FFFu+((v.i>>16)&1u))>>16; return (u16)r; }

DEVI void gload_lds16(const u16* g, u16* l){
    __builtin_amdgcn_global_load_lds((__attribute__((address_space(1))) void*)g,
                                     (__attribute__((address_space(3))) void*)l,
                                     16, 0, 0);
}

// ---------------------------------------------------------------------------
// fp32 -> bf16 elementwise (X ingest). 4 elems/thread.
// ---------------------------------------------------------------------------
__global__ __launch_bounds__(256)
void cvt_bf16(const float* __restrict__ in, u16* __restrict__ out)
{
    const int i = (blockIdx.x * 256 + threadIdx.x) * 4;
    float4 v = *(const float4*)&in[i];
    ushort4 o;
    o.x = f2b(v.x); o.y = f2b(v.y); o.z = f2b(v.z); o.w = f2b(v.w);
    *(ushort4*)&out[i] = o;
}

// ---------------------------------------------------------------------------
// fp32 [R,C] -> bf16 [C,R] transpose (weight ingest). 64x64 LDS tiles.
// ---------------------------------------------------------------------------
__global__ __launch_bounds__(256)
void cvt_transpose(const float* __restrict__ in, u16* __restrict__ out, int R, int C)
{
    __shared__ __align__(16) u16 tile[64*72];
    const int rb = blockIdx.x*64, cb = blockIdx.y*64;
    const int t = threadIdx.x;
    const int r = t >> 3, c0 = (t & 7) * 8;
    #pragma unroll
    for (int rr = 0; rr < 2; rr++) {
        const int row = r + rr*32;
        float4 a = *(const float4*)&in[(long)(rb + row)*C + cb + c0];
        float4 b = *(const float4*)&in[(long)(rb + row)*C + cb + c0 + 4];
        u16* tp = &tile[row*72 + c0];
        tp[0]=f2b(a.x); tp[1]=f2b(a.y); tp[2]=f2b(a.z); tp[3]=f2b(a.w);
        tp[4]=f2b(b.x); tp[5]=f2b(b.y); tp[6]=f2b(b.z); tp[7]=f2b(b.w);
    }
    __syncthreads();
    #pragma unroll
    for (int rr = 0; rr < 2; rr++) {
        const int cr = r + rr*32;
        u16 tmp[8];
        #pragma unroll
        for (int j = 0; j < 8; j++) tmp[j] = tile[(c0 + j)*72 + cr];
        *(uint4*)&out[(long)(cb + cr)*R + rb + c0] = *(uint4*)tmp;
    }
}

// ---------------------------------------------------------------------------
// GEMM: C[M,N] = A[M,K] @ Bt[N,K]^T + bias (+ residual | GELU). bf16 in/out,
// fp32 accum, fp32 bias. 128x128 tile, BK=32, 4 waves (each 64x64 = 4x4 MFMA).
// EPI: 0 = bias, 1 = bias + residual(bf16), 2 = bias + exact GELU.
// ---------------------------------------------------------------------------
template<int EPI>
__global__ __launch_bounds__(256)
void gemm_bt(const u16* __restrict__ A, const u16* __restrict__ Bt,
             const float* __restrict__ bias, const u16* __restrict__ Res,
             u16* __restrict__ C, int M, int N, int K)
{
    __shared__ __align__(16) u16 As[128*32];
    __shared__ __align__(16) u16 Bs[128*32];
    const int tid  = threadIdx.x;
    const int wave = tid >> 6, lane = tid & 63;
    const int tm = blockIdx.x * 128, tn = blockIdx.y * 128;

    const int srow = lane >> 2;          // row within 16-row chunk
    const int scol = (lane & 3) * 8;     // k-offset (8 bf16 = 16B)
    const u16* gA0 = A  + (long)(tm + wave*16 + srow)*K + scol;
    const u16* gA1 = gA0 + (long)64*K;
    const u16* gB0 = Bt + (long)(tn + wave*16 + srow)*K + scol;
    const u16* gB1 = gB0 + (long)64*K;
    u16* lA0 = As + (wave*16)*32;
    u16* lA1 = As + (wave*16 + 64)*32;
    u16* lB0 = Bs + (wave*16)*32;
    u16* lB1 = Bs + (wave*16 + 64)*32;

    const int wm = (wave >> 1) * 64, wn = (wave & 1) * 64;
    const int fr = lane & 15, fq = lane >> 4;

    f32x4 acc[4][4] = {};
    for (int k0 = 0; k0 < K; k0 += 32) {
        __syncthreads();
        gload_lds16(gA0 + k0, lA0);
        gload_lds16(gA1 + k0, lA1);
        gload_lds16(gB0 + k0, lB0);
        gload_lds16(gB1 + k0, lB1);
        __syncthreads();
        bf16x8 af[4], bfr[4];
        #pragma unroll
        for (int i = 0; i < 4; i++)
            af[i]  = *(const bf16x8*)&As[(wm + i*16 + fr)*32 + fq*8];
        #pragma unroll
        for (int j = 0; j < 4; j++)
            bfr[j] = *(const bf16x8*)&Bs[(wn + j*16 + fr)*32 + fq*8];
        #pragma unroll
        for (int i = 0; i < 4; i++)
            #pragma unroll
            for (int j = 0; j < 4; j++)
                acc[i][j] = __builtin_amdgcn_mfma_f32_16x16x32_bf16(af[i], bfr[j], acc[i][j], 0, 0, 0);
    }

    #pragma unroll
    for (int i = 0; i < 4; i++) {
        const int row = tm + wm + i*16 + fq*4;
        #pragma unroll
        for (int j = 0; j < 4; j++) {
            const int col = tn + wn + j*16 + fr;
            const float bv = bias[col];
            #pragma unroll
            for (int r = 0; r < 4; r++) {
                float v = acc[i][j][r] + bv;
                const long idx = (long)(row + r)*N + col;
                if (EPI == 1) v += b2f(Res[idx]);
                if (EPI == 2) v = 0.5f * v * (1.0f + erff(v * 0.70710678f));
                C[idx] = f2b(v);
            }
        }
    }
}

// ---------------------------------------------------------------------------
// Flash attention, causal. block = (qtile, head, batch); 4 waves x 16 q-rows.
// qkv layout: [tok][3072] bf16; Q cols h*64, K 1024+h*64, V 2048+h*64.
// ---------------------------------------------------------------------------
__global__ __launch_bounds__(256)
void attn_kernel(const u16* __restrict__ qkv, u16* __restrict__ O)
{
    constexpr float RSCALE = 0.125f;                 // 1/sqrt(64)
    constexpr float LOG2E  = 1.4426950408889634f;
    __shared__ __align__(16) u16 Qs[64*72];
    __shared__ __align__(16) u16 Ks[64*72];
    __shared__ __align__(16) u16 Vs[64*72];          // V^T, XOR-swizzled
    __shared__ __align__(16) u16 Ps[4][16*72];       // per-wave P scratch

    const int tid = threadIdx.x, wave = tid >> 6, lane = tid & 63;
    const int qt = blockIdx.x, h = blockIdx.y, b = blockIdx.z;
    const long base = (long)b*2048*3072 + h*64;
    const int fr = lane & 15, fq = lane >> 4;

    { // load Q tile once
        const int r = tid >> 3, c = (tid & 7) * 8;
        #pragma unroll
        for (int rr = 0; rr < 2; rr++) {
            uint4 v = *(const uint4*)&qkv[base + (long)(qt*64 + r + rr*32)*3072 + c];
            *(uint4*)&Qs[(r + rr*32)*72 + c] = v;
        }
    }
    __syncthreads();

    f32x4 o[4] = {};
    float mrow[4], lrow[4];
    #pragma unroll
    for (int r = 0; r < 4; r++) { mrow[r] = -1e30f; lrow[r] = 0.f; }

    for (int kt = 0; kt <= qt; kt++) {
        __syncthreads();
        { // stage K row-major (stride 72) and V transposed+swizzled
            const int r = tid >> 3, c = (tid & 7) * 8;
            #pragma unroll
            for (int rr = 0; rr < 2; rr++) {
                const int row = r + rr*32;
                uint4 kv = *(const uint4*)&qkv[base + 1024 + (long)(kt*64 + row)*3072 + c];
                *(uint4*)&Ks[row*72 + c] = kv;
                uint4 vv = *(const uint4*)&qkv[base + 2048 + (long)(kt*64 + row)*3072 + c];
                u16 tmp[8]; *(uint4*)tmp = vv;
                #pragma unroll
                for (int j = 0; j < 8; j++) {
                    const int d = c + j;
                    Vs[d*72 + (row ^ (d & 56))] = tmp[j];
                }
            }
        }
        __syncthreads();

        // S = (Q K^T) * scale  — wave's 16 rows x 64 cols
        f32x4 s[4] = {};
        bf16x8 aq[2];
        #pragma unroll
        for (int ks = 0; ks < 2; ks++)
            aq[ks] = *(const bf16x8*)&Qs[(wave*16 + fr)*72 + ks*32 + fq*8];
        #pragma unroll
        for (int nt = 0; nt < 4; nt++)
            #pragma unroll
            for (int ks = 0; ks < 2; ks++) {
                bf16x8 bk = *(const bf16x8*)&Ks[(nt*16 + fr)*72 + ks*32 + fq*8];
                s[nt] = __builtin_amdgcn_mfma_f32_16x16x32_bf16(aq[ks], bk, s[nt], 0, 0, 0);
            }

        const int qrow0 = qt*64 + wave*16 + fq*4;
        float sv[4][4];
        #pragma unroll
        for (int nt = 0; nt < 4; nt++) {
            const int col = kt*64 + nt*16 + fr;
            #pragma unroll
            for (int r = 0; r < 4; r++) {
                float v = s[nt][r] * RSCALE;
                if (kt == qt && col > qrow0 + r) v = -1e30f;
                sv[nt][r] = v;
            }
        }
        // online softmax per row (rows live across 16 lanes of a quad group)
        #pragma unroll
        for (int r = 0; r < 4; r++) {
            float mx = fmaxf(fmaxf(sv[0][r], sv[1][r]), fmaxf(sv[2][r], sv[3][r]));
            #pragma unroll
            for (int off = 8; off >= 1; off >>= 1) mx = fmaxf(mx, __shfl_xor(mx, off, 16));
            const float mnew  = fmaxf(mrow[r], mx);
            const float alpha = exp2f((mrow[r] - mnew) * LOG2E);
            float psum = 0.f;
            #pragma unroll
            for (int nt = 0; nt < 4; nt++) {
                const float p = exp2f((sv[nt][r] - mnew) * LOG2E);
                sv[nt][r] = p; psum += p;
            }
            #pragma unroll
            for (int off = 8; off >= 1; off >>= 1) psum += __shfl_xor(psum, off, 16);
            lrow[r] = lrow[r]*alpha + psum;
            mrow[r] = mnew;
            #pragma unroll
            for (int dt = 0; dt < 4; dt++) o[dt][r] *= alpha;
        }
        // P: C-layout -> LDS -> A-layout
        #pragma unroll
        for (int nt = 0; nt < 4; nt++)
            #pragma unroll
            for (int r = 0; r < 4; r++)
                Ps[wave][(fq*4 + r)*72 + nt*16 + fr] = f2b(sv[nt][r]);
        __syncthreads();

        bf16x8 ap[2];
        #pragma unroll
        for (int kk = 0; kk < 2; kk++)
            ap[kk] = *(const bf16x8*)&Ps[wave][fr*72 + kk*32 + fq*8];
        #pragma unroll
        for (int dt = 0; dt < 4; dt++) {
            const int d = dt*16 + fr;
            #pragma unroll
            for (int kk = 0; kk < 2; kk++) {
                const int kb = (kk*32 + fq*8) ^ (d & 56);
                bf16x8 bv = *(const bf16x8*)&Vs[d*72 + kb];
                o[dt] = __builtin_amdgcn_mfma_f32_16x16x32_bf16(ap[kk], bv, o[dt], 0, 0, 0);
            }
        }
    }

    const long orow0 = (long)b*2048 + qt*64 + wave*16 + fq*4;
    #pragma unroll
    for (int dt = 0; dt < 4; dt++) {
        const int col = h*64 + dt*16 + fr;
        #pragma unroll
        for (int r = 0; r < 4; r++)
            O[(orow0 + r)*1024 + col] = f2b(o[dt][r] / lrow[r]);
    }
}

// ---------------------------------------------------------------------------
// LayerNorm over 1024 cols; bf16 in, fp32 gamma/beta; OUTF32 selects output.
// ---------------------------------------------------------------------------
template<int OUTF32>
__global__ __launch_bounds__(256)
void ln_kernel(const u16* __restrict__ X, const float* __restrict__ G,
               const float* __restrict__ B, void* __restrict__ Yv)
{
    __shared__ float red[8];
    const int tid = threadIdx.x;
    const long row = blockIdx.x;
    const u16* x = X + row*1024;
    ushort4 u = *(const ushort4*)&x[tid*4];
    const float v0 = b2f(u.x), v1 = b2f(u.y), v2 = b2f(u.z), v3 = b2f(u.w);
    float s = v0+v1+v2+v3;
    float q = v0*v0+v1*v1+v2*v2+v3*v3;
    #pragma unroll
    for (int off = 32; off >= 1; off >>= 1) {
        s += __shfl_xor(s, off, 64);
        q += __shfl_xor(q, off, 64);
    }
    const int wv = tid >> 6;
    if ((tid & 63) == 0) { red[wv*2] = s; red[wv*2+1] = q; }
    __syncthreads();
    s = red[0]+red[2]+red[4]+red[6];
    q = red[1]+red[3]+red[5]+red[7];
    const float mu = s * (1.f/1024.f);
    const float rstd = rsqrtf(fmaxf(q*(1.f/1024.f) - mu*mu, 0.f) + 1e-5f);
    float4 g4 = *(const float4*)&G[tid*4];
    float4 b4 = *(const float4*)&B[tid*4];
    const float y0 = (v0-mu)*rstd*g4.x + b4.x;
    const float y1 = (v1-mu)*rstd*g4.y + b4.y;
    const float y2 = (v2-mu)*rstd*g4.z + b4.z;
    const float y3 = (v3-mu)*rstd*g4.w + b4.w;
    if (OUTF32) {
        float4 o = make_float4(y0, y1, y2, y3);
        *(float4*)&((float*)Yv)[row*1024 + tid*4] = o;
    } else {
        ushort4 o;
        o.x = f2b(y0); o.y = f2b(y1); o.z = f2b(y2); o.w = f2b(y3);
        *(ushort4*)&((u16*)Yv)[row*1024 + tid*4] = o;
    }
}

// ---------------------------------------------------------------------------
// Workspace budget: 48 MiB of d_ws + d_out (16 MiB) used as scratch for
// W1T/W2T (dead before the final LN writes d_out). Liveness-audited:
//   Xbf  [ 0, 8) MiB  live cvt .. Wo-gemm(Res)
//   WqkvT[ 8,14)      live cvt .. QKV-gemm
//   WoT  [14,16)      live cvt .. Wo-gemm
//   QKV  [16,40)      live QKV-gemm .. attn
//   AO   [40,48)      live attn .. Wo-gemm
//   S1   [16,24)      live Wo-gemm .. LN1      (over dead QKV head)
//   H1   [ 0, 8)      live LN1 .. FF2          (over dead Xbf)
//   Gbuf [ 8,40)      live FF1 .. FF2          (over dead WqkvT/WoT/QKV)
//   S2   [40,48)      live FF2 .. LN2          (over dead AO)
//   W1T  d_out[ 0, 8) MiB, W2T d_out[ 8,16) — dead before LN2 writes d_out
// ---------------------------------------------------------------------------
extern "C" void kernel_launch(void* const* d_in, const int* in_sizes, int n_in,
                              void* d_out, int out_size, void* d_ws, size_t ws_size,
                              hipStream_t stream)
{
    const float* X    = (const float*)d_in[0];
    const float* Wqkv = (const float*)d_in[1];
    const float* bqkv = (const float*)d_in[2];
    const float* Wo   = (const float*)d_in[3];
    const float* bo   = (const float*)d_in[4];
    const float* W1   = (const float*)d_in[5];
    const float* b1   = (const float*)d_in[6];
    const float* W2   = (const float*)d_in[7];
    const float* b2   = (const float*)d_in[8];
    const float* g1   = (const float*)d_in[9];
    const float* be1  = (const float*)d_in[10];
    const float* g2   = (const float*)d_in[11];
    const float* be2  = (const float*)d_in[12];
    float* out = (float*)d_out;

    char* ws = (char*)d_ws;
    u16* Xbf   = (u16*)(ws + 0);
    u16* WqkvT = (u16*)(ws + 8388608);
    u16* WoT   = (u16*)(ws + 14680064);
    u16* QKV   = (u16*)(ws + 16777216);
    u16* AO    = (u16*)(ws + 41943040);
    u16* S1    = (u16*)(ws + 16777216);
    u16* H1    = (u16*)(ws + 0);
    u16* Gbuf  = (u16*)(ws + 8388608);
    u16* S2    = (u16*)(ws + 41943040);
    u16* W1T   = (u16*)d_out;                  // 4096x1024 bf16 = 8 MiB
    u16* W2T   = (u16*)d_out + 4194304;        // 1024x4096 bf16 = 8 MiB

    // ingest: fp32 -> bf16 (X elementwise; weights transposed to [N,K])
    cvt_bf16<<<4096, 256, 0, stream>>>(X, Xbf);
    cvt_transpose<<<dim3(16, 48), 256, 0, stream>>>(Wqkv, WqkvT, 1024, 3072);
    cvt_transpose<<<dim3(16, 16), 256, 0, stream>>>(Wo,   WoT,   1024, 1024);
    cvt_transpose<<<dim3(16, 64), 256, 0, stream>>>(W1,   W1T,   1024, 4096);
    cvt_transpose<<<dim3(64, 16), 256, 0, stream>>>(W2,   W2T,   4096, 1024);

    // qkv = X @ Wqkv + b
    gemm_bt<0><<<dim3(32, 24), 256, 0, stream>>>(Xbf, WqkvT, bqkv, nullptr, QKV, 4096, 3072, 1024);
    // attention
    attn_kernel<<<dim3(32, 16, 2), 256, 0, stream>>>(QKV, AO);
    // S1 = AO @ Wo + bo + X
    gemm_bt<1><<<dim3(32, 8), 256, 0, stream>>>(AO, WoT, bo, Xbf, S1, 4096, 1024, 1024);
    // H1 = LN1(S1)  (bf16)
    ln_kernel<0><<<4096, 256, 0, stream>>>(S1, g1, be1, H1);
    // G = gelu(H1 @ W1 + b1)
    gemm_bt<2><<<dim3(32, 32), 256, 0, stream>>>(H1, W1T, b1, nullptr, Gbuf, 4096, 4096, 1024);
    // S2 = G @ W2 + b2 + H1
    gemm_bt<1><<<dim3(32, 8), 256, 0, stream>>>(Gbuf, W2T, b2, H1, S2, 4096, 1024, 4096);
    // out = LN2(S2)  (fp32)
    ln_kernel<1><<<4096, 256, 0, stream>>>(S2, g2, be2, out);
}

// Round 4
// 462.142 us; speedup vs baseline: 1.1880x; 1.1880x over previous
//
#include <hip/hip_runtime.h>
#include <cmath>

typedef unsigned short u16;
typedef __bf16 bf16x8 __attribute__((ext_vector_type(8)));
typedef float f32x4 __attribute__((ext_vector_type(4)));

#define DEVI __device__ __forceinline__

DEVI float b2f(u16 u){ union{unsigned int i; float f;} v; v.i=(unsigned int)u<<16; return v.f; }
DEVI u16 f2b(float f){ union{unsigned int i; float f;} v; v.f=f;
    unsigned int r=(v.i+0x7FFFu+((v.i>>16)&1u))>>16; return (u16)r; }

DEVI void gload_lds16(const u16* g, u16* l){
    __builtin_amdgcn_global_load_lds((__attribute__((address_space(1))) void*)g,
                                     (__attribute__((address_space(3))) void*)l,
                                     16, 0, 0);
}

// ---------------------------------------------------------------------------
// fp32 -> bf16 elementwise (X ingest). 4 elems/thread.
// ---------------------------------------------------------------------------
__global__ __launch_bounds__(256)
void cvt_bf16(const float* __restrict__ in, u16* __restrict__ out)
{
    const int i = (blockIdx.x * 256 + threadIdx.x) * 4;
    float4 v = *(const float4*)&in[i];
    ushort4 o;
    o.x = f2b(v.x); o.y = f2b(v.y); o.z = f2b(v.z); o.w = f2b(v.w);
    *(ushort4*)&out[i] = o;
}

// ---------------------------------------------------------------------------
// fp32 [R,C] -> bf16 [C,R] transpose (weight ingest). 64x64 LDS tiles.
// ---------------------------------------------------------------------------
__global__ __launch_bounds__(256)
void cvt_transpose(const float* __restrict__ in, u16* __restrict__ out, int R, int C)
{
    __shared__ __align__(16) u16 tile[64*72];
    const int rb = blockIdx.x*64, cb = blockIdx.y*64;
    const int t = threadIdx.x;
    const int r = t >> 3, c0 = (t & 7) * 8;
    #pragma unroll
    for (int rr = 0; rr < 2; rr++) {
        const int row = r + rr*32;
        float4 a = *(const float4*)&in[(long)(rb + row)*C + cb + c0];
        float4 b = *(const float4*)&in[(long)(rb + row)*C + cb + c0 + 4];
        u16* tp = &tile[row*72 + c0];
        tp[0]=f2b(a.x); tp[1]=f2b(a.y); tp[2]=f2b(a.z); tp[3]=f2b(a.w);
        tp[4]=f2b(b.x); tp[5]=f2b(b.y); tp[6]=f2b(b.z); tp[7]=f2b(b.w);
    }
    __syncthreads();
    #pragma unroll
    for (int rr = 0; rr < 2; rr++) {
        const int cr = r + rr*32;
        u16 tmp[8];
        #pragma unroll
        for (int j = 0; j < 8; j++) tmp[j] = tile[(c0 + j)*72 + cr];
        *(uint4*)&out[(long)(cb + cr)*R + rb + c0] = *(uint4*)tmp;
    }
}

// ---------------------------------------------------------------------------
// GEMM: C[M,N] = A[M,K] @ Bt[N,K]^T + bias (+ residual | GELU). bf16 in/out,
// fp32 accum, fp32 bias. 128x128 tile, BK=32, 4 waves (each 64x64 = 4x4 MFMA).
// EPI: 0 = bias, 1 = bias + residual(bf16), 2 = bias + exact GELU.
// ---------------------------------------------------------------------------
template<int EPI>
__global__ __launch_bounds__(256)
void gemm_bt(const u16* __restrict__ A, const u16* __restrict__ Bt,
             const float* __restrict__ bias, const u16* __restrict__ Res,
             u16* __restrict__ C, int M, int N, int K)
{
    __shared__ __align__(16) u16 As[128*32];
    __shared__ __align__(16) u16 Bs[128*32];
    const int tid  = threadIdx.x;
    const int wave = tid >> 6, lane = tid & 63;
    const int tm = blockIdx.x * 128, tn = blockIdx.y * 128;

    const int srow = lane >> 2;          // row within 16-row chunk
    const int scol = (lane & 3) * 8;     // k-offset (8 bf16 = 16B)
    const u16* gA0 = A  + (long)(tm + wave*16 + srow)*K + scol;
    const u16* gA1 = gA0 + (long)64*K;
    const u16* gB0 = Bt + (long)(tn + wave*16 + srow)*K + scol;
    const u16* gB1 = gB0 + (long)64*K;
    u16* lA0 = As + (wave*16)*32;
    u16* lA1 = As + (wave*16 + 64)*32;
    u16* lB0 = Bs + (wave*16)*32;
    u16* lB1 = Bs + (wave*16 + 64)*32;

    const int wm = (wave >> 1) * 64, wn = (wave & 1) * 64;
    const int fr = lane & 15, fq = lane >> 4;

    f32x4 acc[4][4] = {};
    for (int k0 = 0; k0 < K; k0 += 32) {
        __syncthreads();
        gload_lds16(gA0 + k0, lA0);
        gload_lds16(gA1 + k0, lA1);
        gload_lds16(gB0 + k0, lB0);
        gload_lds16(gB1 + k0, lB1);
        __syncthreads();
        bf16x8 af[4], bfr[4];
        #pragma unroll
        for (int i = 0; i < 4; i++)
            af[i]  = *(const bf16x8*)&As[(wm + i*16 + fr)*32 + fq*8];
        #pragma unroll
        for (int j = 0; j < 4; j++)
            bfr[j] = *(const bf16x8*)&Bs[(wn + j*16 + fr)*32 + fq*8];
        #pragma unroll
        for (int i = 0; i < 4; i++)
            #pragma unroll
            for (int j = 0; j < 4; j++)
                acc[i][j] = __builtin_amdgcn_mfma_f32_16x16x32_bf16(af[i], bfr[j], acc[i][j], 0, 0, 0);
    }

    #pragma unroll
    for (int i = 0; i < 4; i++) {
        const int row = tm + wm + i*16 + fq*4;
        #pragma unroll
        for (int j = 0; j < 4; j++) {
            const int col = tn + wn + j*16 + fr;
            const float bv = bias[col];
            #pragma unroll
            for (int r = 0; r < 4; r++) {
                float v = acc[i][j][r] + bv;
                const long idx = (long)(row + r)*N + col;
                if (EPI == 1) v += b2f(Res[idx]);
                if (EPI == 2) v = 0.5f * v * (1.0f + erff(v * 0.70710678f));
                C[idx] = f2b(v);
            }
        }
    }
}

// ---------------------------------------------------------------------------
// Flash attention v2, causal. block = (qtile, head, batch); 4 waves x 16 rows.
// Computes S^T = K Q^T so softmax rows live per-lane (2-shuffle reduction).
// P converted C->A layout via wave-private packed-dword LDS roundtrip.
// Q pre-scaled by 1/sqrt(64) (exact bf16 exponent shift).
// ---------------------------------------------------------------------------
__global__ __launch_bounds__(256)
void attn_kernel(const u16* __restrict__ qkv, u16* __restrict__ O)
{
    constexpr float LOG2E = 1.4426950408889634f;
    __shared__ __align__(16) u16 Qs[64*72];
    __shared__ __align__(16) u16 Ks[64*72];
    __shared__ __align__(16) u16 Vs[64*72];          // V^T, XOR-swizzled
    __shared__ __align__(16) u16 Ps[4][16*72];       // per-wave P [q][key]

    const int tid = threadIdx.x, wave = tid >> 6, lane = tid & 63;
    const int qt = blockIdx.x, h = blockIdx.y, b = blockIdx.z;
    const long base = (long)b*2048*3072 + h*64;
    const int fr = lane & 15, fq = lane >> 4;

    { // load Q tile once, pre-scaled by 0.125
        const int r = tid >> 3, c = (tid & 7) * 8;
        #pragma unroll
        for (int rr = 0; rr < 2; rr++) {
            uint4 v = *(const uint4*)&qkv[base + (long)(qt*64 + r + rr*32)*3072 + c];
            u16 tmp[8]; *(uint4*)tmp = v;
            u16* qp = &Qs[(r + rr*32)*72 + c];
            #pragma unroll
            for (int j = 0; j < 8; j++) qp[j] = f2b(b2f(tmp[j]) * 0.125f);
        }
    }
    __syncthreads();

    // hoisted Q B-fragments: lane n=fr -> q-row wave*16+fr
    bf16x8 bq[2];
    #pragma unroll
    for (int ks = 0; ks < 2; ks++)
        bq[ks] = *(const bf16x8*)&Qs[(wave*16 + fr)*72 + ks*32 + fq*8];

    const int q_glob = qt*64 + wave*16 + fr;   // this lane's softmax row
    f32x4 o[4] = {};
    float m_i = -1e30f, l_i = 0.f;

    for (int kt = 0; kt <= qt; kt++) {
        __syncthreads();   // all waves done reading Ks/Vs of previous tile
        { // stage K row-major (stride 72) and V transposed+swizzled
            const int r = tid >> 3, c = (tid & 7) * 8;
            #pragma unroll
            for (int rr = 0; rr < 2; rr++) {
                const int row = r + rr*32;
                uint4 kv = *(const uint4*)&qkv[base + 1024 + (long)(kt*64 + row)*3072 + c];
                *(uint4*)&Ks[row*72 + c] = kv;
                uint4 vv = *(const uint4*)&qkv[base + 2048 + (long)(kt*64 + row)*3072 + c];
                u16 tmp[8]; *(uint4*)tmp = vv;
                #pragma unroll
                for (int j = 0; j < 8; j++) {
                    const int d = c + j;
                    Vs[d*72 + (row ^ (d & 56))] = tmp[j];
                }
            }
        }
        __syncthreads();

        // S^T = K Q^T : A = K rows (m=key), B = Q^T (n=q-row)
        f32x4 st[4] = {};
        #pragma unroll
        for (int nt = 0; nt < 4; nt++)
            #pragma unroll
            for (int ks = 0; ks < 2; ks++) {
                bf16x8 ak = *(const bf16x8*)&Ks[(nt*16 + fr)*72 + ks*32 + fq*8];
                st[nt] = __builtin_amdgcn_mfma_f32_16x16x32_bf16(ak, bq[ks], st[nt], 0, 0, 0);
            }

        // mask + per-lane softmax over this lane's 16 key-values (row = q_glob)
        float sv[4][4];
        float mx = -1e30f;
        #pragma unroll
        for (int nt = 0; nt < 4; nt++) {
            #pragma unroll
            for (int r = 0; r < 4; r++) {
                const int key = kt*64 + nt*16 + fq*4 + r;
                float v = st[nt][r];
                if (key > q_glob) v = -1e30f;
                sv[nt][r] = v;
                mx = fmaxf(mx, v);
            }
        }
        mx = fmaxf(mx, __shfl_xor(mx, 16, 64));
        mx = fmaxf(mx, __shfl_xor(mx, 32, 64));
        const float mnew  = fmaxf(m_i, mx);
        const float alpha = exp2f((m_i - mnew) * LOG2E);
        float ps = 0.f;
        #pragma unroll
        for (int nt = 0; nt < 4; nt++)
            #pragma unroll
            for (int r = 0; r < 4; r++) {
                const float p = exp2f((sv[nt][r] - mnew) * LOG2E);
                sv[nt][r] = p; ps += p;
            }
        ps += __shfl_xor(ps, 16, 64);
        ps += __shfl_xor(ps, 32, 64);
        l_i = l_i * alpha + ps;
        m_i = mnew;

        // rescale O accumulator: its row q' = fq*4+r, alpha lives at lane fr=q'
        #pragma unroll
        for (int r = 0; r < 4; r++) {
            const float ar = __shfl(alpha, (lane & 48) + fq*4 + r, 64);
            #pragma unroll
            for (int dt = 0; dt < 4; dt++) o[dt][r] *= ar;
        }

        // P -> wave-private LDS [q=fr][key], packed dwords (keys fq*4+2d, +1)
        u16* pw = Ps[wave];
        #pragma unroll
        for (int nt = 0; nt < 4; nt++)
            #pragma unroll
            for (int d = 0; d < 2; d++) {
                const unsigned pk = (unsigned)f2b(sv[nt][2*d]) |
                                    ((unsigned)f2b(sv[nt][2*d+1]) << 16);
                *(unsigned*)&pw[fr*72 + nt*16 + fq*4 + 2*d] = pk;
            }
        __asm__ volatile("" ::: "memory");  // keep write->read order (same wave)

        bf16x8 ap[2];
        #pragma unroll
        for (int kk = 0; kk < 2; kk++)
            ap[kk] = *(const bf16x8*)&pw[fr*72 + kk*32 + fq*8];

        #pragma unroll
        for (int dt = 0; dt < 4; dt++) {
            const int d = dt*16 + fr;
            #pragma unroll
            for (int kk = 0; kk < 2; kk++) {
                const int kb = (kk*32 + fq*8) ^ (d & 56);
                bf16x8 bv = *(const bf16x8*)&Vs[d*72 + kb];
                o[dt] = __builtin_amdgcn_mfma_f32_16x16x32_bf16(ap[kk], bv, o[dt], 0, 0, 0);
            }
        }
    }

    // epilogue: O row q' = fq*4+r; l lives at lane fr=q'
    float lro[4];
    #pragma unroll
    for (int r = 0; r < 4; r++)
        lro[r] = __shfl(l_i, (lane & 48) + fq*4 + r, 64);
    const long orow0 = (long)b*2048 + qt*64 + wave*16 + fq*4;
    #pragma unroll
    for (int dt = 0; dt < 4; dt++) {
        const int col = h*64 + dt*16 + fr;
        #pragma unroll
        for (int r = 0; r < 4; r++)
            O[(orow0 + r)*1024 + col] = f2b(o[dt][r] / lro[r]);
    }
}

// ---------------------------------------------------------------------------
// LayerNorm over 1024 cols; bf16 in, fp32 gamma/beta; OUTF32 selects output.
// ---------------------------------------------------------------------------
template<int OUTF32>
__global__ __launch_bounds__(256)
void ln_kernel(const u16* __restrict__ X, const float* __restrict__ G,
               const float* __restrict__ B, void* __restrict__ Yv)
{
    __shared__ float red[8];
    const int tid = threadIdx.x;
    const long row = blockIdx.x;
    const u16* x = X + row*1024;
    ushort4 u = *(const ushort4*)&x[tid*4];
    const float v0 = b2f(u.x), v1 = b2f(u.y), v2 = b2f(u.z), v3 = b2f(u.w);
    float s = v0+v1+v2+v3;
    float q = v0*v0+v1*v1+v2*v2+v3*v3;
    #pragma unroll
    for (int off = 32; off >= 1; off >>= 1) {
        s += __shfl_xor(s, off, 64);
        q += __shfl_xor(q, off, 64);
    }
    const int wv = tid >> 6;
    if ((tid & 63) == 0) { red[wv*2] = s; red[wv*2+1] = q; }
    __syncthreads();
    s = red[0]+red[2]+red[4]+red[6];
    q = red[1]+red[3]+red[5]+red[7];
    const float mu = s * (1.f/1024.f);
    const float rstd = rsqrtf(fmaxf(q*(1.f/1024.f) - mu*mu, 0.f) + 1e-5f);
    float4 g4 = *(const float4*)&G[tid*4];
    float4 b4 = *(const float4*)&B[tid*4];
    const float y0 = (v0-mu)*rstd*g4.x + b4.x;
    const float y1 = (v1-mu)*rstd*g4.y + b4.y;
    const float y2 = (v2-mu)*rstd*g4.z + b4.z;
    const float y3 = (v3-mu)*rstd*g4.w + b4.w;
    if (OUTF32) {
        float4 o = make_float4(y0, y1, y2, y3);
        *(float4*)&((float*)Yv)[row*1024 + tid*4] = o;
    } else {
        ushort4 o;
        o.x = f2b(y0); o.y = f2b(y1); o.z = f2b(y2); o.w = f2b(y3);
        *(ushort4*)&((u16*)Yv)[row*1024 + tid*4] = o;
    }
}

// ---------------------------------------------------------------------------
// Workspace: 48 MiB of d_ws + d_out (16 MiB) as scratch for W1T/W2T.
// Liveness identical to Round 3 (audited there, passed).
// ---------------------------------------------------------------------------
extern "C" void kernel_launch(void* const* d_in, const int* in_sizes, int n_in,
                              void* d_out, int out_size, void* d_ws, size_t ws_size,
                              hipStream_t stream)
{
    const float* X    = (const float*)d_in[0];
    const float* Wqkv = (const float*)d_in[1];
    const float* bqkv = (const float*)d_in[2];
    const float* Wo   = (const float*)d_in[3];
    const float* bo   = (const float*)d_in[4];
    const float* W1   = (const float*)d_in[5];
    const float* b1   = (const float*)d_in[6];
    const float* W2   = (const float*)d_in[7];
    const float* b2   = (const float*)d_in[8];
    const float* g1   = (const float*)d_in[9];
    const float* be1  = (const float*)d_in[10];
    const float* g2   = (const float*)d_in[11];
    const float* be2  = (const float*)d_in[12];
    float* out = (float*)d_out;

    char* ws = (char*)d_ws;
    u16* Xbf   = (u16*)(ws + 0);
    u16* WqkvT = (u16*)(ws + 8388608);
    u16* WoT   = (u16*)(ws + 14680064);
    u16* QKV   = (u16*)(ws + 16777216);
    u16* AO    = (u16*)(ws + 41943040);
    u16* S1    = (u16*)(ws + 16777216);
    u16* H1    = (u16*)(ws + 0);
    u16* Gbuf  = (u16*)(ws + 8388608);
    u16* S2    = (u16*)(ws + 41943040);
    u16* W1T   = (u16*)d_out;                  // 4096x1024 bf16 = 8 MiB
    u16* W2T   = (u16*)d_out + 4194304;        // 1024x4096 bf16 = 8 MiB

    cvt_bf16<<<4096, 256, 0, stream>>>(X, Xbf);
    cvt_transpose<<<dim3(16, 48), 256, 0, stream>>>(Wqkv, WqkvT, 1024, 3072);
    cvt_transpose<<<dim3(16, 16), 256, 0, stream>>>(Wo,   WoT,   1024, 1024);
    cvt_transpose<<<dim3(16, 64), 256, 0, stream>>>(W1,   W1T,   1024, 4096);
    cvt_transpose<<<dim3(64, 16), 256, 0, stream>>>(W2,   W2T,   4096, 1024);

    gemm_bt<0><<<dim3(32, 24), 256, 0, stream>>>(Xbf, WqkvT, bqkv, nullptr, QKV, 4096, 3072, 1024);
    attn_kernel<<<dim3(32, 16, 2), 256, 0, stream>>>(QKV, AO);
    gemm_bt<1><<<dim3(32, 8), 256, 0, stream>>>(AO, WoT, bo, Xbf, S1, 4096, 1024, 1024);
    ln_kernel<0><<<4096, 256, 0, stream>>>(S1, g1, be1, H1);
    gemm_bt<2><<<dim3(32, 32), 256, 0, stream>>>(H1, W1T, b1, nullptr, Gbuf, 4096, 4096, 1024);
    gemm_bt<1><<<dim3(32, 8), 256, 0, stream>>>(Gbuf, W2T, b2, H1, S2, 4096, 1024, 4096);
    ln_kernel<1><<<4096, 256, 0, stream>>>(S2, g2, be2, out);
}

// Round 5
// 415.051 us; speedup vs baseline: 1.3227x; 1.1135x over previous
//
#include <hip/hip_runtime.h>
#include <cmath>

typedef unsigned short u16;
typedef __bf16 bf16x8 __attribute__((ext_vector_type(8)));
typedef float f32x4 __attribute__((ext_vector_type(4)));

#define DEVI __device__ __forceinline__

DEVI float b2f(u16 u){ union{unsigned int i; float f;} v; v.i=(unsigned int)u<<16; return v.f; }
DEVI u16 f2b(float f){ union{unsigned int i; float f;} v; v.f=f;
    unsigned int r=(v.i+0x7FFFu+((v.i>>16)&1u))>>16; return (u16)r; }

DEVI void gload_lds16(const u16* g, u16* l){
    __builtin_amdgcn_global_load_lds((__attribute__((address_space(1))) void*)g,
                                     (__attribute__((address_space(3))) void*)l,
                                     16, 0, 0);
}

// ---------------------------------------------------------------------------
// fp32 -> bf16 elementwise (X ingest). 4 elems/thread.
// ---------------------------------------------------------------------------
__global__ __launch_bounds__(256)
void cvt_bf16(const float* __restrict__ in, u16* __restrict__ out)
{
    const int i = (blockIdx.x * 256 + threadIdx.x) * 4;
    float4 v = *(const float4*)&in[i];
    ushort4 o;
    o.x = f2b(v.x); o.y = f2b(v.y); o.z = f2b(v.z); o.w = f2b(v.w);
    *(ushort4*)&out[i] = o;
}

// ---------------------------------------------------------------------------
// fp32 [R,C] -> bf16 [C,R] transpose (weight ingest). 64x64 LDS tiles.
// ---------------------------------------------------------------------------
__global__ __launch_bounds__(256)
void cvt_transpose(const float* __restrict__ in, u16* __restrict__ out, int R, int C)
{
    __shared__ __align__(16) u16 tile[64*72];
    const int rb = blockIdx.x*64, cb = blockIdx.y*64;
    const int t = threadIdx.x;
    const int r = t >> 3, c0 = (t & 7) * 8;
    #pragma unroll
    for (int rr = 0; rr < 2; rr++) {
        const int row = r + rr*32;
        float4 a = *(const float4*)&in[(long)(rb + row)*C + cb + c0];
        float4 b = *(const float4*)&in[(long)(rb + row)*C + cb + c0 + 4];
        u16* tp = &tile[row*72 + c0];
        tp[0]=f2b(a.x); tp[1]=f2b(a.y); tp[2]=f2b(a.z); tp[3]=f2b(a.w);
        tp[4]=f2b(b.x); tp[5]=f2b(b.y); tp[6]=f2b(b.z); tp[7]=f2b(b.w);
    }
    __syncthreads();
    #pragma unroll
    for (int rr = 0; rr < 2; rr++) {
        const int cr = r + rr*32;
        u16 tmp[8];
        #pragma unroll
        for (int j = 0; j < 8; j++) tmp[j] = tile[(c0 + j)*72 + cr];
        *(uint4*)&out[(long)(cb + cr)*R + rb + c0] = *(uint4*)tmp;
    }
}

// ---------------------------------------------------------------------------
// GEMM: C[M,N] = A[M,K] @ Bt[N,K]^T + bias (+ residual | GELU). bf16 in/out,
// fp32 accum. Tile BM x 128, BK=64 staged as two 32-wide panels so
// global_load_lds stays wave-contiguous. 4 waves; wave tile (BM/2) x 64.
// EPI: 0 = bias, 1 = bias + residual(bf16), 2 = bias + tanh-GELU.
// ---------------------------------------------------------------------------
template<int EPI, int BM>
__global__ __launch_bounds__(256)
void gemm_bt(const u16* __restrict__ A, const u16* __restrict__ Bt,
             const float* __restrict__ bias, const u16* __restrict__ Res,
             u16* __restrict__ C, int M, int N, int K)
{
    constexpr int RM = BM / 32;          // MFMA row-tiles per wave
    constexpr int NA = (BM / 16) * 2 / 4; // A-chunks per wave (1KB each)
    __shared__ __align__(16) u16 As[BM*64];
    __shared__ __align__(16) u16 Bs[128*64];
    const int tid  = threadIdx.x;
    const int wave = tid >> 6, lane = tid & 63;
    const int tm = blockIdx.x * BM, tn = blockIdx.y * 128;

    // staging: each global_load_lds = 64 lanes x 16B = 16 rows x 32 elems
    const int rs = lane >> 2, cs = (lane & 3) * 8;
    const u16* gA[NA]; u16* lA[NA];
    #pragma unroll
    for (int i = 0; i < NA; i++) {
        const int c = wave + i*4;                 // chunk id
        const int p = c / (BM/16), rb = c % (BM/16);
        gA[i] = A + (long)(tm + rb*16 + rs)*K + p*32 + cs;
        lA[i] = As + p*(BM*32) + rb*512;
    }
    const u16* gB[4]; u16* lB[4];
    #pragma unroll
    for (int i = 0; i < 4; i++) {
        const int c = wave + i*4;
        const int p = c >> 3, rb = c & 7;
        gB[i] = Bt + (long)(tn + rb*16 + rs)*K + p*32 + cs;
        lB[i] = Bs + p*(128*32) + rb*512;
    }

    const int wm = (wave >> 1) * (BM/2), wn = (wave & 1) * 64;
    const int fr = lane & 15, fq = lane >> 4;

    f32x4 acc[RM][4] = {};
    for (int k0 = 0; k0 < K; k0 += 64) {
        __syncthreads();
        #pragma unroll
        for (int i = 0; i < NA; i++) gload_lds16(gA[i] + k0, lA[i]);
        #pragma unroll
        for (int i = 0; i < 4; i++)  gload_lds16(gB[i] + k0, lB[i]);
        __syncthreads();
        #pragma unroll
        for (int p = 0; p < 2; p++) {
            bf16x8 af[RM], bfr[4];
            #pragma unroll
            for (int i = 0; i < RM; i++)
                af[i]  = *(const bf16x8*)&As[p*(BM*32) + (wm + i*16 + fr)*32 + fq*8];
            #pragma unroll
            for (int j = 0; j < 4; j++)
                bfr[j] = *(const bf16x8*)&Bs[p*(128*32) + (wn + j*16 + fr)*32 + fq*8];
            #pragma unroll
            for (int i = 0; i < RM; i++)
                #pragma unroll
                for (int j = 0; j < 4; j++)
                    acc[i][j] = __builtin_amdgcn_mfma_f32_16x16x32_bf16(af[i], bfr[j], acc[i][j], 0, 0, 0);
        }
    }

    #pragma unroll
    for (int i = 0; i < RM; i++) {
        const int row = tm + wm + i*16 + fq*4;
        #pragma unroll
        for (int j = 0; j < 4; j++) {
            const int col = tn + wn + j*16 + fr;
            const float bv = bias[col];
            #pragma unroll
            for (int r = 0; r < 4; r++) {
                float v = acc[i][j][r] + bv;
                const long idx = (long)(row + r)*N + col;
                if (EPI == 1) v += b2f(Res[idx]);
                if (EPI == 2) {
                    // gelu(x) = x * t/(t+1), t = exp(2*0.79788456(x+0.044715x^3))
                    const float u = v + 0.044715f*v*v*v;
                    const float t = exp2f(u * 2.302208f); // 2*0.79788456*log2(e)
                    v = v * t * __builtin_amdgcn_rcpf(t + 1.f);
                }
                C[idx] = f2b(v);
            }
        }
    }
}

// ---------------------------------------------------------------------------
// Flash attention v2, causal. block = (qtile, head, batch); 4 waves x 16 rows.
// Computes S^T = K Q^T so softmax rows live per-lane (2-shuffle reduction).
// P converted C->A layout via wave-private packed-dword LDS roundtrip.
// Q pre-scaled by 1/sqrt(64).
// ---------------------------------------------------------------------------
__global__ __launch_bounds__(256)
void attn_kernel(const u16* __restrict__ qkv, u16* __restrict__ O)
{
    constexpr float LOG2E = 1.4426950408889634f;
    __shared__ __align__(16) u16 Qs[64*72];
    __shared__ __align__(16) u16 Ks[64*72];
    __shared__ __align__(16) u16 Vs[64*72];          // V^T, XOR-swizzled
    __shared__ __align__(16) u16 Ps[4][16*72];       // per-wave P [q][key]

    const int tid = threadIdx.x, wave = tid >> 6, lane = tid & 63;
    const int qt = blockIdx.x, h = blockIdx.y, b = blockIdx.z;
    const long base = (long)b*2048*3072 + h*64;
    const int fr = lane & 15, fq = lane >> 4;

    { // load Q tile once, pre-scaled by 0.125
        const int r = tid >> 3, c = (tid & 7) * 8;
        #pragma unroll
        for (int rr = 0; rr < 2; rr++) {
            uint4 v = *(const uint4*)&qkv[base + (long)(qt*64 + r + rr*32)*3072 + c];
            u16 tmp[8]; *(uint4*)tmp = v;
            u16* qp = &Qs[(r + rr*32)*72 + c];
            #pragma unroll
            for (int j = 0; j < 8; j++) qp[j] = f2b(b2f(tmp[j]) * 0.125f);
        }
    }
    __syncthreads();

    bf16x8 bq[2];
    #pragma unroll
    for (int ks = 0; ks < 2; ks++)
        bq[ks] = *(const bf16x8*)&Qs[(wave*16 + fr)*72 + ks*32 + fq*8];

    const int q_glob = qt*64 + wave*16 + fr;   // this lane's softmax row
    f32x4 o[4] = {};
    float m_i = -1e30f, l_i = 0.f;

    for (int kt = 0; kt <= qt; kt++) {
        __syncthreads();
        { // stage K row-major (stride 72) and V transposed+swizzled
            const int r = tid >> 3, c = (tid & 7) * 8;
            #pragma unroll
            for (int rr = 0; rr < 2; rr++) {
                const int row = r + rr*32;
                uint4 kv = *(const uint4*)&qkv[base + 1024 + (long)(kt*64 + row)*3072 + c];
                *(uint4*)&Ks[row*72 + c] = kv;
                uint4 vv = *(const uint4*)&qkv[base + 2048 + (long)(kt*64 + row)*3072 + c];
                u16 tmp[8]; *(uint4*)tmp = vv;
                #pragma unroll
                for (int j = 0; j < 8; j++) {
                    const int d = c + j;
                    Vs[d*72 + (row ^ (d & 56))] = tmp[j];
                }
            }
        }
        __syncthreads();

        // S^T = K Q^T
        f32x4 st[4] = {};
        #pragma unroll
        for (int nt = 0; nt < 4; nt++)
            #pragma unroll
            for (int ks = 0; ks < 2; ks++) {
                bf16x8 ak = *(const bf16x8*)&Ks[(nt*16 + fr)*72 + ks*32 + fq*8];
                st[nt] = __builtin_amdgcn_mfma_f32_16x16x32_bf16(ak, bq[ks], st[nt], 0, 0, 0);
            }

        float sv[4][4];
        float mx = -1e30f;
        #pragma unroll
        for (int nt = 0; nt < 4; nt++) {
            #pragma unroll
            for (int r = 0; r < 4; r++) {
                const int key = kt*64 + nt*16 + fq*4 + r;
                float v = st[nt][r];
                if (key > q_glob) v = -1e30f;
                sv[nt][r] = v;
                mx = fmaxf(mx, v);
            }
        }
        mx = fmaxf(mx, __shfl_xor(mx, 16, 64));
        mx = fmaxf(mx, __shfl_xor(mx, 32, 64));
        const float mnew  = fmaxf(m_i, mx);
        const float alpha = exp2f((m_i - mnew) * LOG2E);
        float ps = 0.f;
        #pragma unroll
        for (int nt = 0; nt < 4; nt++)
            #pragma unroll
            for (int r = 0; r < 4; r++) {
                const float p = exp2f((sv[nt][r] - mnew) * LOG2E);
                sv[nt][r] = p; ps += p;
            }
        ps += __shfl_xor(ps, 16, 64);
        ps += __shfl_xor(ps, 32, 64);
        l_i = l_i * alpha + ps;
        m_i = mnew;

        #pragma unroll
        for (int r = 0; r < 4; r++) {
            const float ar = __shfl(alpha, (lane & 48) + fq*4 + r, 64);
            #pragma unroll
            for (int dt = 0; dt < 4; dt++) o[dt][r] *= ar;
        }

        u16* pw = Ps[wave];
        #pragma unroll
        for (int nt = 0; nt < 4; nt++)
            #pragma unroll
            for (int d = 0; d < 2; d++) {
                const unsigned pk = (unsigned)f2b(sv[nt][2*d]) |
                                    ((unsigned)f2b(sv[nt][2*d+1]) << 16);
                *(unsigned*)&pw[fr*72 + nt*16 + fq*4 + 2*d] = pk;
            }
        __asm__ volatile("" ::: "memory");

        bf16x8 ap[2];
        #pragma unroll
        for (int kk = 0; kk < 2; kk++)
            ap[kk] = *(const bf16x8*)&pw[fr*72 + kk*32 + fq*8];

        #pragma unroll
        for (int dt = 0; dt < 4; dt++) {
            const int d = dt*16 + fr;
            #pragma unroll
            for (int kk = 0; kk < 2; kk++) {
                const int kb = (kk*32 + fq*8) ^ (d & 56);
                bf16x8 bv = *(const bf16x8*)&Vs[d*72 + kb];
                o[dt] = __builtin_amdgcn_mfma_f32_16x16x32_bf16(ap[kk], bv, o[dt], 0, 0, 0);
            }
        }
    }

    float lro[4];
    #pragma unroll
    for (int r = 0; r < 4; r++)
        lro[r] = __shfl(l_i, (lane & 48) + fq*4 + r, 64);
    const long orow0 = (long)b*2048 + qt*64 + wave*16 + fq*4;
    #pragma unroll
    for (int dt = 0; dt < 4; dt++) {
        const int col = h*64 + dt*16 + fr;
        #pragma unroll
        for (int r = 0; r < 4; r++)
            O[(orow0 + r)*1024 + col] = f2b(o[dt][r] / lro[r]);
    }
}

// ---------------------------------------------------------------------------
// LayerNorm over 1024 cols; bf16 in, fp32 gamma/beta; OUTF32 selects output.
// ---------------------------------------------------------------------------
template<int OUTF32>
__global__ __launch_bounds__(256)
void ln_kernel(const u16* __restrict__ X, const float* __restrict__ G,
               const float* __restrict__ B, void* __restrict__ Yv)
{
    __shared__ float red[8];
    const int tid = threadIdx.x;
    const long row = blockIdx.x;
    const u16* x = X + row*1024;
    ushort4 u = *(const ushort4*)&x[tid*4];
    const float v0 = b2f(u.x), v1 = b2f(u.y), v2 = b2f(u.z), v3 = b2f(u.w);
    float s = v0+v1+v2+v3;
    float q = v0*v0+v1*v1+v2*v2+v3*v3;
    #pragma unroll
    for (int off = 32; off >= 1; off >>= 1) {
        s += __shfl_xor(s, off, 64);
        q += __shfl_xor(q, off, 64);
    }
    const int wv = tid >> 6;
    if ((tid & 63) == 0) { red[wv*2] = s; red[wv*2+1] = q; }
    __syncthreads();
    s = red[0]+red[2]+red[4]+red[6];
    q = red[1]+red[3]+red[5]+red[7];
    const float mu = s * (1.f/1024.f);
    const float rstd = rsqrtf(fmaxf(q*(1.f/1024.f) - mu*mu, 0.f) + 1e-5f);
    float4 g4 = *(const float4*)&G[tid*4];
    float4 b4 = *(const float4*)&B[tid*4];
    const float y0 = (v0-mu)*rstd*g4.x + b4.x;
    const float y1 = (v1-mu)*rstd*g4.y + b4.y;
    const float y2 = (v2-mu)*rstd*g4.z + b4.z;
    const float y3 = (v3-mu)*rstd*g4.w + b4.w;
    if (OUTF32) {
        float4 o = make_float4(y0, y1, y2, y3);
        *(float4*)&((float*)Yv)[row*1024 + tid*4] = o;
    } else {
        ushort4 o;
        o.x = f2b(y0); o.y = f2b(y1); o.z = f2b(y2); o.w = f2b(y3);
        *(ushort4*)&((u16*)Yv)[row*1024 + tid*4] = o;
    }
}

// ---------------------------------------------------------------------------
// Workspace: 48 MiB of d_ws + d_out (16 MiB) as scratch for W1T/W2T.
// Liveness identical to Round 3 (audited, passed).
// ---------------------------------------------------------------------------
extern "C" void kernel_launch(void* const* d_in, const int* in_sizes, int n_in,
                              void* d_out, int out_size, void* d_ws, size_t ws_size,
                              hipStream_t stream)
{
    const float* X    = (const float*)d_in[0];
    const float* Wqkv = (const float*)d_in[1];
    const float* bqkv = (const float*)d_in[2];
    const float* Wo   = (const float*)d_in[3];
    const float* bo   = (const float*)d_in[4];
    const float* W1   = (const float*)d_in[5];
    const float* b1   = (const float*)d_in[6];
    const float* W2   = (const float*)d_in[7];
    const float* b2   = (const float*)d_in[8];
    const float* g1   = (const float*)d_in[9];
    const float* be1  = (const float*)d_in[10];
    const float* g2   = (const float*)d_in[11];
    const float* be2  = (const float*)d_in[12];
    float* out = (float*)d_out;

    char* ws = (char*)d_ws;
    u16* Xbf   = (u16*)(ws + 0);
    u16* WqkvT = (u16*)(ws + 8388608);
    u16* WoT   = (u16*)(ws + 14680064);
    u16* QKV   = (u16*)(ws + 16777216);
    u16* AO    = (u16*)(ws + 41943040);
    u16* S1    = (u16*)(ws + 16777216);
    u16* H1    = (u16*)(ws + 0);
    u16* Gbuf  = (u16*)(ws + 8388608);
    u16* S2    = (u16*)(ws + 41943040);
    u16* W1T   = (u16*)d_out;                  // 4096x1024 bf16 = 8 MiB
    u16* W2T   = (u16*)d_out + 4194304;        // 1024x4096 bf16 = 8 MiB

    cvt_bf16<<<4096, 256, 0, stream>>>(X, Xbf);
    cvt_transpose<<<dim3(16, 48), 256, 0, stream>>>(Wqkv, WqkvT, 1024, 3072);
    cvt_transpose<<<dim3(16, 16), 256, 0, stream>>>(Wo,   WoT,   1024, 1024);
    cvt_transpose<<<dim3(16, 64), 256, 0, stream>>>(W1,   W1T,   1024, 4096);
    cvt_transpose<<<dim3(64, 16), 256, 0, stream>>>(W2,   W2T,   4096, 1024);

    gemm_bt<0,128><<<dim3(32, 24), 256, 0, stream>>>(Xbf, WqkvT, bqkv, nullptr, QKV, 4096, 3072, 1024);
    attn_kernel<<<dim3(32, 16, 2), 256, 0, stream>>>(QKV, AO);
    gemm_bt<1,64><<<dim3(64, 8), 256, 0, stream>>>(AO, WoT, bo, Xbf, S1, 4096, 1024, 1024);
    ln_kernel<0><<<4096, 256, 0, stream>>>(S1, g1, be1, H1);
    gemm_bt<2,128><<<dim3(32, 32), 256, 0, stream>>>(H1, W1T, b1, nullptr, Gbuf, 4096, 4096, 1024);
    gemm_bt<1,64><<<dim3(64, 8), 256, 0, stream>>>(Gbuf, W2T, b2, H1, S2, 4096, 1024, 4096);
    ln_kernel<1><<<4096, 256, 0, stream>>>(S2, g2, be2, out);
}